// Round 1
// baseline (391.438 us; speedup 1.0000x reference)
//
#include <hip/hip_runtime.h>
#include <hip/hip_bf16.h>
#include <math.h>

#define T_TOK 2048
#define HDIM 1024
#define IDIM 4096
#define NEXP 8
#define NTILE 40      // 16 shared + 24 routed (max) 128-row tiles
#define RROWS 3072    // routed rows incl. per-expert 128-padding
#define AROWS 5120    // 2048 shared + 3072 routed rows

typedef unsigned int uint;
typedef unsigned short ushort;
typedef __attribute__((ext_vector_type(4))) float f32x4;
typedef __attribute__((ext_vector_type(8))) short bf16x8;

__device__ __forceinline__ ushort f2bf(float f) {
  union { float f; uint u; } c; c.f = f;
  uint u = c.u;
  return (ushort)((u + 0x7FFFu + ((u >> 16) & 1u)) >> 16);  // RNE
}
__device__ __forceinline__ uint pk2(float a, float b) {
  return (uint)f2bf(a) | ((uint)f2bf(b) << 16);
}
__device__ __forceinline__ uint4 pack8(const float4& a, const float4& b) {
  uint4 r; r.x = pk2(a.x, a.y); r.y = pk2(a.z, a.w);
  r.z = pk2(b.x, b.y); r.w = pk2(b.z, b.w);
  return r;
}

// ---------------- router: logits, top-1, sigmoid, scores out, hs->bf16 ----
__global__ __launch_bounds__(256) void router_kernel(
    const float* __restrict__ hs, const float* __restrict__ rw,
    ushort* __restrict__ Xall, float* __restrict__ scores_out,
    int* __restrict__ eidx, float* __restrict__ sval)
{
  const int wave = threadIdx.x >> 6;
  const int lane = threadIdx.x & 63;
  const int t = blockIdx.x * 4 + wave;
  const float* row = hs + (size_t)t * HDIM;
  float v[16];
  #pragma unroll
  for (int i = 0; i < 16; ++i) {
    v[i] = row[lane + 64 * i];
    Xall[(size_t)t * HDIM + lane + 64 * i] = f2bf(v[i]);
  }
  float logit[8];
  #pragma unroll
  for (int e = 0; e < 8; ++e) {
    const float* wr = rw + e * HDIM;
    float s = 0.f;
    #pragma unroll
    for (int i = 0; i < 16; ++i) s += v[i] * wr[lane + 64 * i];
    #pragma unroll
    for (int off = 32; off; off >>= 1) s += __shfl_xor(s, off, 64);
    logit[e] = s;
  }
  if (lane == 0) {
    int be = 0; float bv = logit[0];
    #pragma unroll
    for (int e = 1; e < 8; ++e) if (logit[e] > bv) { bv = logit[e]; be = e; }
    float sc = 1.f / (1.f + expf(-bv));
    eidx[t] = be; sval[t] = sc;
    #pragma unroll
    for (int e = 0; e < 8; ++e) scores_out[(size_t)e * T_TOK + t] = (e == be) ? sc : 0.f;
  }
}

// ---------------- plan: counts, 128-aligned segments, slots, tile descs ---
__global__ __launch_bounds__(256) void plan_kernel(
    const int* __restrict__ eidx, int* __restrict__ row2tok, int2* __restrict__ tiles)
{
  __shared__ int cnt[8];
  __shared__ int slot[8];
  const int tid = threadIdx.x;
  if (tid < 8) cnt[tid] = 0;
  __syncthreads();
  for (int t = tid; t < T_TOK; t += 256) atomicAdd(&cnt[eidx[t]], 1);
  __syncthreads();
  if (tid == 0) {
    for (int rt0 = 0; rt0 < 16; ++rt0) tiles[rt0] = make_int2(rt0 * 128, -1);
    int o = 0, rt = 16;
    for (int e = 0; e < 8; ++e) {
      slot[e] = o;
      int cap = (cnt[e] + 127) & ~127;
      for (int j = 0; j < cap / 128; ++j) { tiles[rt++] = make_int2(T_TOK + o + j * 128, e); }
      o += cap;
    }
    for (; rt < NTILE; ++rt) tiles[rt] = make_int2(T_TOK + RROWS - 128, 0); // guaranteed-zero rows
  }
  for (int r = tid; r < RROWS; r += 256) row2tok[r] = -1;
  __syncthreads();
  for (int t = tid; t < T_TOK; t += 256) {
    int e = eidx[t];
    int s = atomicAdd(&slot[e], 1);
    row2tok[s] = t;
  }
}

// ---------------- gather: X'[slot] = score * hs[tok] (bf16), 0 for pad ----
__global__ __launch_bounds__(256) void gather_kernel(
    const float* __restrict__ hs, const int* __restrict__ row2tok,
    const float* __restrict__ sval, ushort* __restrict__ Xall)
{
  const int r = blockIdx.x;
  const int t = row2tok[r];
  const int c0 = threadIdx.x * 4;
  ushort4 o;
  if (t >= 0) {
    const float sc = sval[t];
    float4 v = *(const float4*)(hs + (size_t)t * HDIM + c0);
    o.x = f2bf(sc * v.x); o.y = f2bf(sc * v.y); o.z = f2bf(sc * v.z); o.w = f2bf(sc * v.w);
  } else { o.x = o.y = o.z = o.w = 0; }
  *(ushort4*)(Xall + (size_t)(T_TOK + r) * HDIM + c0) = o;
}

// ---------------- GEMM1: act = silu(X*Wg^T) * (X*Wu^T), bf16 out ---------
__global__ __launch_bounds__(256, 2) void gemm1_kernel(
    const ushort* __restrict__ Xall,
    const float* __restrict__ w_gate, const float* __restrict__ w_up,
    const float* __restrict__ ws_gate, const float* __restrict__ ws_up,
    const int2* __restrict__ tiles, ushort* __restrict__ actall)
{
  __shared__ __align__(16) ushort As[2][128][40];
  __shared__ __align__(16) ushort Bg[2][128][40];
  __shared__ __align__(16) ushort Bu[2][128][40];

  const int2 td = tiles[blockIdx.y];
  const int row0 = td.x;
  const int e = td.y;
  const float* __restrict__ gbase = (e < 0) ? ws_gate : w_gate + (size_t)e * IDIM * HDIM;
  const float* __restrict__ ubase = (e < 0) ? ws_up   : w_up   + (size_t)e * IDIM * HDIM;
  const int col0 = blockIdx.x * 128;

  const int tid = threadIdx.x;
  const int lane = tid & 63;
  const int wave = tid >> 6;
  const int wm = wave >> 1, wn = wave & 1;

  const int srow = tid >> 1;
  const int scol = (tid & 1) * 16;

  const ushort* aptr = Xall + (size_t)(row0 + srow) * HDIM + scol;
  const float*  gptr = gbase + (size_t)(col0 + srow) * HDIM + scol;
  const float*  uptr = ubase + (size_t)(col0 + srow) * HDIM + scol;

  f32x4 accg[4][4] = {};
  f32x4 accu[4][4] = {};

  uint4 la0, la1, lg0, lg1, lu0, lu1;
  auto stage_load = [&](int k0) {
    const ushort* ap = aptr + k0;
    la0 = *(const uint4*)ap; la1 = *(const uint4*)(ap + 8);
    const float4* gp = (const float4*)(gptr + k0);
    lg0 = pack8(gp[0], gp[1]); lg1 = pack8(gp[2], gp[3]);
    const float4* up = (const float4*)(uptr + k0);
    lu0 = pack8(up[0], up[1]); lu1 = pack8(up[2], up[3]);
  };
  auto stage_write = [&](int b) {
    *(uint4*)&As[b][srow][scol] = la0; *(uint4*)&As[b][srow][scol + 8] = la1;
    *(uint4*)&Bg[b][srow][scol] = lg0; *(uint4*)&Bg[b][srow][scol + 8] = lg1;
    *(uint4*)&Bu[b][srow][scol] = lu0; *(uint4*)&Bu[b][srow][scol + 8] = lu1;
  };

  stage_load(0); stage_write(0);
  __syncthreads();

  const int rA = wm * 64 + (lane & 15);
  const int rB = wn * 64 + (lane & 15);
  const int koff = (lane >> 4) * 8;

  for (int ks = 0; ks < HDIM / 32; ++ks) {
    const int b = ks & 1;
    if (ks < HDIM / 32 - 1) stage_load((ks + 1) * 32);
    bf16x8 af[4], gf[4], uf[4];
    #pragma unroll
    for (int m = 0; m < 4; ++m) af[m] = *(const bf16x8*)&As[b][rA + m * 16][koff];
    #pragma unroll
    for (int n = 0; n < 4; ++n) {
      gf[n] = *(const bf16x8*)&Bg[b][rB + n * 16][koff];
      uf[n] = *(const bf16x8*)&Bu[b][rB + n * 16][koff];
    }
    #pragma unroll
    for (int m = 0; m < 4; ++m)
      #pragma unroll
      for (int n = 0; n < 4; ++n) {
        accg[m][n] = __builtin_amdgcn_mfma_f32_16x16x32_bf16(af[m], gf[n], accg[m][n], 0, 0, 0);
        accu[m][n] = __builtin_amdgcn_mfma_f32_16x16x32_bf16(af[m], uf[n], accu[m][n], 0, 0, 0);
      }
    if (ks < HDIM / 32 - 1) stage_write(b ^ 1);
    __syncthreads();
  }

  const int rbase = row0 + wm * 64 + ((lane >> 4) << 2);
  const int cbase = col0 + wn * 64 + (lane & 15);
  #pragma unroll
  for (int m = 0; m < 4; ++m)
    #pragma unroll
    for (int n = 0; n < 4; ++n)
      #pragma unroll
      for (int j = 0; j < 4; ++j) {
        float g = accg[m][n][j];
        float u = accu[m][n][j];
        float s = g / (1.f + __expf(-g)) * u;   // silu(g)*u
        actall[(size_t)(rbase + m * 16 + j) * IDIM + cbase + n * 16] = f2bf(s);
      }
}

// ---------------- GEMM2: out = act * Wd^T; shared->d_out, routed->bufr ---
__global__ __launch_bounds__(256, 2) void gemm2_kernel(
    const ushort* __restrict__ actall,
    const float* __restrict__ w_down, const float* __restrict__ ws_down,
    const int2* __restrict__ tiles, const int* __restrict__ row2tok,
    float* __restrict__ out, float* __restrict__ bufr)
{
  __shared__ __align__(16) ushort As[2][64][40];
  __shared__ __align__(16) ushort Bs[2][128][40];

  const int rt64 = blockIdx.y;
  const int2 td = tiles[rt64 >> 1];
  const int row0 = td.x + (rt64 & 1) * 64;
  const int e = td.y;
  const float* __restrict__ bbase = (e < 0) ? ws_down : w_down + (size_t)e * HDIM * IDIM;
  const int col0 = blockIdx.x * 128;

  const int tid = threadIdx.x;
  const int lane = tid & 63;
  const int wave = tid >> 6;
  const int wm = wave >> 1, wn = wave & 1;

  const int arow = tid >> 2, acol = (tid & 3) * 8;
  const int brow = tid >> 1, bcol = (tid & 1) * 16;

  const ushort* aptr = actall + (size_t)(row0 + arow) * IDIM + acol;
  const float*  bptr = bbase + (size_t)(col0 + brow) * IDIM + bcol;

  f32x4 acc[2][4] = {};

  uint4 la, lb0, lb1;
  auto stage_load = [&](int k0) {
    la = *(const uint4*)(aptr + k0);
    const float4* bp = (const float4*)(bptr + k0);
    lb0 = pack8(bp[0], bp[1]); lb1 = pack8(bp[2], bp[3]);
  };
  auto stage_write = [&](int b) {
    *(uint4*)&As[b][arow][acol] = la;
    *(uint4*)&Bs[b][brow][bcol] = lb0; *(uint4*)&Bs[b][brow][bcol + 8] = lb1;
  };

  stage_load(0); stage_write(0);
  __syncthreads();

  const int rA = wm * 32 + (lane & 15);
  const int rB = wn * 64 + (lane & 15);
  const int koff = (lane >> 4) * 8;

  for (int ks = 0; ks < IDIM / 32; ++ks) {
    const int b = ks & 1;
    if (ks < IDIM / 32 - 1) stage_load((ks + 1) * 32);
    bf16x8 af[2], bfr[4];
    #pragma unroll
    for (int m = 0; m < 2; ++m) af[m] = *(const bf16x8*)&As[b][rA + m * 16][koff];
    #pragma unroll
    for (int n = 0; n < 4; ++n) bfr[n] = *(const bf16x8*)&Bs[b][rB + n * 16][koff];
    #pragma unroll
    for (int m = 0; m < 2; ++m)
      #pragma unroll
      for (int n = 0; n < 4; ++n)
        acc[m][n] = __builtin_amdgcn_mfma_f32_16x16x32_bf16(af[m], bfr[n], acc[m][n], 0, 0, 0);
    if (ks < IDIM / 32 - 1) stage_write(b ^ 1);
    __syncthreads();
  }

  const int rloc = wm * 32 + ((lane >> 4) << 2);
  const int cbase = col0 + wn * 64 + (lane & 15);
  #pragma unroll
  for (int m = 0; m < 2; ++m)
    #pragma unroll
    for (int j = 0; j < 4; ++j) {
      const int r = row0 + rloc + m * 16 + j;
      if (e < 0) {
        #pragma unroll
        for (int n = 0; n < 4; ++n)
          out[(size_t)r * HDIM + cbase + n * 16] = acc[m][n][j];
      } else {
        const int t = row2tok[r - T_TOK];
        if (t >= 0) {
          #pragma unroll
          for (int n = 0; n < 4; ++n)
            bufr[(size_t)t * HDIM + cbase + n * 16] = acc[m][n][j];
        }
      }
    }
}

// ---------------- final: out += routed ------------------------------------
__global__ __launch_bounds__(256) void add_kernel(
    float* __restrict__ out, const float* __restrict__ bufr)
{
  const size_t i = ((size_t)blockIdx.x * 256 + threadIdx.x) * 4;
  float4 a = *(float4*)(out + i);
  const float4 b = *(const float4*)(bufr + i);
  a.x += b.x; a.y += b.y; a.z += b.z; a.w += b.w;
  *(float4*)(out + i) = a;
}

extern "C" void kernel_launch(void* const* d_in, const int* in_sizes, int n_in,
                              void* d_out, int out_size, void* d_ws, size_t ws_size,
                              hipStream_t stream)
{
  const float* hs      = (const float*)d_in[0];
  const float* rw      = (const float*)d_in[1];
  const float* w_gate  = (const float*)d_in[2];
  const float* w_up    = (const float*)d_in[3];
  const float* w_down  = (const float*)d_in[4];
  const float* ws_gate = (const float*)d_in[5];
  const float* ws_up   = (const float*)d_in[6];
  const float* ws_down = (const float*)d_in[7];

  float* out = (float*)d_out;
  float* scores_out = out + (size_t)T_TOK * HDIM;

  char* ws = (char*)d_ws;
  ushort* Xall   = (ushort*)ws;                       // AROWS*HDIM*2   = 10485760
  ushort* actall = (ushort*)(ws + 10485760);          // AROWS*IDIM*2   = 41943040
  float*  bufr   = (float*)(ws + 52428800);           // T*H*4          = 8388608
  int*    eidx   = (int*)(ws + 60817408);             // 8192
  float*  sval   = (float*)(ws + 60825600);           // 8192
  int*    r2t    = (int*)(ws + 60833792);             // 12288
  int2*   tiles  = (int2*)(ws + 60846080);            // 320

  router_kernel<<<T_TOK / 4, 256, 0, stream>>>(hs, rw, Xall, scores_out, eidx, sval);
  plan_kernel<<<1, 256, 0, stream>>>(eidx, r2t, tiles);
  gather_kernel<<<RROWS, 256, 0, stream>>>(hs, r2t, sval, Xall);
  gemm1_kernel<<<dim3(IDIM / 128, NTILE), 256, 0, stream>>>(
      Xall, w_gate, w_up, ws_gate, ws_up, tiles, actall);
  gemm2_kernel<<<dim3(HDIM / 128, NTILE * 2), 256, 0, stream>>>(
      actall, w_down, ws_down, tiles, r2t, out, bufr);
  add_kernel<<<(T_TOK * HDIM) / 1024, 256, 0, stream>>>(out, bufr);
}